// Round 1
// baseline (36.337 us; speedup 1.0000x reference)
//
#include <hip/hip_runtime.h>
#include <math.h>

constexpr int Hd = 128;   // hidden
constexpr int Nd = 64;    // state size
constexpr int Ld = 4096;  // sequence length
constexpr int Bd = 32;    // batch

// ---------------------------------------------------------------------------
// Kernel 1: K[h,l] = 2*Re( sum_n Bt[h,n] * exp(dtA[h,n]*l) ), l = 0..L-1
// grid (H, 4): block (h, quarter of l-range); 256 threads; each thread owns
// l = part*1024 + t + 256*i, i=0..3, stepping p *= exp(dtA*256).
// ---------------------------------------------------------------------------
__global__ __launch_bounds__(256) void k_kernelK(
    const float* __restrict__ log_dt,
    const float* __restrict__ log_A_real,
    const float* __restrict__ A_imag,
    const float* __restrict__ C_re,
    const float* __restrict__ C_im,
    float* __restrict__ Kout)
{
    const int h    = blockIdx.x;
    const int part = blockIdx.y;       // 0..3
    const int t    = threadIdx.x;      // 0..255
    const int base = part * 1024;

    __shared__ float sBtr[Nd], sBti[Nd], sDre[Nd], sDim[Nd], sSr[Nd], sSi[Nd];

    if (t < Nd) {
        const int n = t;
        float dt   = expf(log_dt[h]);
        float a_re = -expf(log_A_real[h*Nd + n]);
        float a_im = A_imag[h*Nd + n];
        float dre  = dt * a_re, dim = dt * a_im;
        // e = exp(dtA)
        float er = expf(dre);
        float sn, cs; sincosf(dim, &sn, &cs);
        float em1_re = er*cs - 1.0f;
        float em1_im = er*sn;
        // (e-1)/A = (e-1)*conj(A)/|A|^2
        float inv  = 1.0f / (a_re*a_re + a_im*a_im);
        float q_re = (em1_re*a_re + em1_im*a_im) * inv;
        float q_im = (em1_im*a_re - em1_re*a_im) * inv;
        float c_re = C_re[h*Nd + n], c_im = C_im[h*Nd + n];
        sBtr[n] = c_re*q_re - c_im*q_im;
        sBti[n] = c_re*q_im + c_im*q_re;
        sDre[n] = dre;  sDim[n] = dim;
        // step = exp(256*dtA)
        float er2 = expf(256.0f*dre);
        float s2, c2; sincosf(256.0f*dim, &s2, &c2);
        sSr[n] = er2*c2;  sSi[n] = er2*s2;
    }
    __syncthreads();

    float acc0 = 0.f, acc1 = 0.f, acc2 = 0.f, acc3 = 0.f;
    const float l0 = (float)(base + t);
    #pragma unroll 4
    for (int n = 0; n < Nd; ++n) {
        const float btr = sBtr[n], bti = sBti[n];
        const float sr  = sSr[n],  si  = sSi[n];
        // p = exp(dtA * l0)
        float er = expf(sDre[n] * l0);
        float sn, cs; sincosf(sDim[n] * l0, &sn, &cs);
        float pr = er*cs, pi = er*sn;

        acc0 += btr*pr - bti*pi;
        float tmp = pr*sr - pi*si; pi = pr*si + pi*sr; pr = tmp;
        acc1 += btr*pr - bti*pi;
        tmp = pr*sr - pi*si; pi = pr*si + pi*sr; pr = tmp;
        acc2 += btr*pr - bti*pi;
        tmp = pr*sr - pi*si; pi = pr*si + pi*sr; pr = tmp;
        acc3 += btr*pr - bti*pi;
    }
    float* Krow = Kout + (size_t)h * Ld + base + t;
    Krow[0]   = 2.0f*acc0;
    Krow[256] = 2.0f*acc1;
    Krow[512] = 2.0f*acc2;
    Krow[768] = 2.0f*acc3;
}

// ---------------------------------------------------------------------------
// Kernel 2: for each (b,h):
//   s  = sum_m K[h,m]*data[b, L-1-m]
//   ks = sum_m K[h,m]
//   y  = W_in[h]*s + b_in[h]*ks + (data[b,L-1]*W_in[h] + b_in[h])*D[h]
//   ygelu[b,h] = gelu_tanh(y)
// grid (B, 32): block = 256 threads = 4 waves; wave w handles h = hg*4+w.
// ---------------------------------------------------------------------------
__global__ __launch_bounds__(256) void k_conv(
    const float* __restrict__ data,
    const float* __restrict__ Kmat,
    const float* __restrict__ W_in,
    const float* __restrict__ b_in,
    const float* __restrict__ Dvec,
    float* __restrict__ ygelu)
{
    const int b    = blockIdx.x;
    const int hg   = blockIdx.y;        // 0..31
    const int tid  = threadIdx.x;
    const int wave = tid >> 6;
    const int lane = tid & 63;
    const int h    = hg*4 + wave;

    __shared__ float xrev[Ld];
    for (int i = tid; i < Ld; i += 256)
        xrev[i] = data[(size_t)b*Ld + (Ld - 1 - i)];
    __syncthreads();

    const float* Krow = Kmat + (size_t)h * Ld;
    float s = 0.0f, ks = 0.0f;
    #pragma unroll 4
    for (int m = lane; m < Ld; m += 64) {
        float kv = Krow[m];
        s  += kv * xrev[m];
        ks += kv;
    }
    #pragma unroll
    for (int off = 32; off >= 1; off >>= 1) {
        s  += __shfl_xor(s,  off);
        ks += __shfl_xor(ks, off);
    }
    if (lane == 0) {
        float w  = W_in[h], bi = b_in[h];
        float ulast = data[(size_t)b*Ld + (Ld - 1)] * w + bi;
        float y  = w*s + bi*ks + ulast*Dvec[h];
        // jax.nn.gelu (approximate=True, tanh form)
        float y3 = y*y*y;
        float g  = 0.5f*y*(1.0f + tanhf(0.7978845608028654f*(y + 0.044715f*y3)));
        ygelu[b*Hd + h] = g;
    }
}

// ---------------------------------------------------------------------------
// Kernel 3: per batch b: z = y @ W_glu + b_glu (128->256);
//   glu = z[:128] * sigmoid(z[128:]); out[b] = glu . W_out + b_out
// grid B, 256 threads (one per z column).
// ---------------------------------------------------------------------------
__global__ __launch_bounds__(256) void k_glu_out(
    const float* __restrict__ ygelu,
    const float* __restrict__ W_glu,
    const float* __restrict__ b_glu,
    const float* __restrict__ W_out,
    const float* __restrict__ b_out,
    float* __restrict__ out)
{
    const int b = blockIdx.x;
    const int j = threadIdx.x;          // 0..255
    __shared__ float y[Hd];
    __shared__ float z[2*Hd];
    __shared__ float partial[4];

    if (j < Hd) y[j] = ygelu[b*Hd + j];
    __syncthreads();

    float zz = b_glu[j];
    #pragma unroll 8
    for (int hh = 0; hh < Hd; ++hh)
        zz += y[hh] * W_glu[hh*(2*Hd) + j];
    z[j] = zz;
    __syncthreads();

    float g = 0.0f;
    if (j < Hd) {
        float sig = 1.0f / (1.0f + expf(-z[j + Hd]));
        g = z[j] * sig * W_out[j];
    }
    #pragma unroll
    for (int off = 32; off >= 1; off >>= 1) g += __shfl_xor(g, off);
    if ((j & 63) == 0) partial[j >> 6] = g;
    __syncthreads();
    if (j == 0) out[b] = partial[0] + partial[1] + partial[2] + partial[3] + b_out[0];
}

// ---------------------------------------------------------------------------
extern "C" void kernel_launch(void* const* d_in, const int* in_sizes, int n_in,
                              void* d_out, int out_size, void* d_ws, size_t ws_size,
                              hipStream_t stream) {
    const float* data   = (const float*)d_in[0];
    const float* W_in   = (const float*)d_in[1];
    const float* b_in   = (const float*)d_in[2];
    const float* log_dt = (const float*)d_in[3];
    const float* log_A  = (const float*)d_in[4];
    const float* A_im   = (const float*)d_in[5];
    const float* C_re   = (const float*)d_in[6];
    const float* C_im   = (const float*)d_in[7];
    const float* Dvec   = (const float*)d_in[8];
    const float* W_glu  = (const float*)d_in[9];
    const float* b_glu  = (const float*)d_in[10];
    const float* W_out  = (const float*)d_in[11];
    const float* b_out  = (const float*)d_in[12];
    float* out = (float*)d_out;

    float* K     = (float*)d_ws;            // Hd*Ld floats = 2 MB
    float* ygelu = K + (size_t)Hd * Ld;     // Bd*Hd floats

    k_kernelK<<<dim3(Hd, 4), 256, 0, stream>>>(log_dt, log_A, A_im, C_re, C_im, K);
    k_conv   <<<dim3(Bd, 32), 256, 0, stream>>>(data, K, W_in, b_in, Dvec, ygelu);
    k_glu_out<<<Bd, 256, 0, stream>>>(ygelu, W_glu, b_glu, W_out, b_out, out);
}

// Round 2
// 30.846 us; speedup vs baseline: 1.1780x; 1.1780x over previous
//
#include <hip/hip_runtime.h>
#include <math.h>

constexpr int Hd = 128;   // hidden
constexpr int Nd = 64;    // state size
constexpr int Ld = 4096;  // sequence length
constexpr int Bd = 32;    // batch

// ---------------------------------------------------------------------------
// Kernel 1: K[h,l] = 2*Re( sum_n Bt[h,n] * exp(dtA[h,n]*l) ), l = 0..L-1
// grid (H, 4); 256 threads; thread owns l = part*1024 + t + 256*i, i=0..3,
// stepping p *= exp(dtA*256).
// Phase computed as revolutions in f64, fed to HW v_sin/v_cos (rev semantics).
// Magnitude via exp2f (single v_exp_f32). No libm range reduction anywhere.
// ---------------------------------------------------------------------------
__global__ __launch_bounds__(256) void k_kernelK(
    const float* __restrict__ log_dt,
    const float* __restrict__ log_A_real,
    const float* __restrict__ A_imag,
    const float* __restrict__ C_re,
    const float* __restrict__ C_im,
    float* __restrict__ Kout)
{
    const int h    = blockIdx.x;
    const int part = blockIdx.y;       // 0..3
    const int t    = threadIdx.x;      // 0..255
    const int base = part * 1024;

    __shared__ float  sBtr[Nd], sBti[Nd], sDreL2[Nd], sSr[Nd], sSi[Nd];
    __shared__ double sRev[Nd];        // dim / (2*pi), f64

    if (t < Nd) {
        const int n = t;
        float dt   = expf(log_dt[h]);
        float a_re = -expf(log_A_real[h*Nd + n]);
        float a_im = A_imag[h*Nd + n];
        float dre  = dt * a_re, dim = dt * a_im;
        // e = exp(dtA)   (small args: fast path)
        float er = expf(dre);
        float sn, cs; sincosf(dim, &sn, &cs);
        float em1_re = er*cs - 1.0f;
        float em1_im = er*sn;
        // (e-1)/A = (e-1)*conj(A)/|A|^2
        float inv  = 1.0f / (a_re*a_re + a_im*a_im);
        float q_re = (em1_re*a_re + em1_im*a_im) * inv;
        float q_im = (em1_im*a_re - em1_re*a_im) * inv;
        float c_re = C_re[h*Nd + n], c_im = C_im[h*Nd + n];
        sBtr[n] = c_re*q_re - c_im*q_im;
        sBti[n] = c_re*q_im + c_im*q_re;

        float dreL2 = dre * 1.4426950408889634f;          // dre*log2(e)
        double rev  = (double)dt * (double)a_im * 0.15915494309189535; // dim/2pi
        sDreL2[n] = dreL2;
        sRev[n]   = rev;
        // step256 = exp(dtA*256)
        float er2 = exp2f(dreL2 * 256.0f);
        double r2 = rev * 256.0;  r2 -= floor(r2);
        float fr2 = (float)r2;
        float s2  = __builtin_amdgcn_sinf(fr2);           // sin(2*pi*fr2)
        float c2  = __builtin_amdgcn_cosf(fr2);
        sSr[n] = er2*c2;  sSi[n] = er2*s2;
    }
    __syncthreads();

    float acc0 = 0.f, acc1 = 0.f, acc2 = 0.f, acc3 = 0.f;
    const float  l0f = (float)(base + t);
    const double l0d = (double)(base + t);
    #pragma unroll 4
    for (int n = 0; n < Nd; ++n) {
        const float btr = sBtr[n], bti = sBti[n];
        const float sr  = sSr[n],  si  = sSi[n];
        // p = exp(dtA * l0): magnitude via exp2, phase via HW sin/cos (rev)
        float  er = exp2f(sDreL2[n] * l0f);
        double rv = sRev[n] * l0d;  rv -= floor(rv);
        float  fr = (float)rv;
        float  sn = __builtin_amdgcn_sinf(fr);
        float  cs = __builtin_amdgcn_cosf(fr);
        float  pr = er*cs, pi = er*sn;

        acc0 += btr*pr - bti*pi;
        float tmp = pr*sr - pi*si; pi = pr*si + pi*sr; pr = tmp;
        acc1 += btr*pr - bti*pi;
        tmp = pr*sr - pi*si; pi = pr*si + pi*sr; pr = tmp;
        acc2 += btr*pr - bti*pi;
        tmp = pr*sr - pi*si; pi = pr*si + pi*sr; pr = tmp;
        acc3 += btr*pr - bti*pi;
    }
    float* Krow = Kout + (size_t)h * Ld + base + t;
    Krow[0]   = 2.0f*acc0;
    Krow[256] = 2.0f*acc1;
    Krow[512] = 2.0f*acc2;
    Krow[768] = 2.0f*acc3;
}

// ---------------------------------------------------------------------------
// Kernel 2: for each (b,h):
//   s  = sum_m K[h,m]*data[b, L-1-m];  ks = sum_m K[h,m]
//   y  = W_in[h]*s + b_in[h]*ks + (data[b,L-1]*W_in[h] + b_in[h])*D[h]
//   ygelu[b,h] = gelu_tanh(y)
// grid (B, 32): 256 threads = 4 waves; wave w handles h = hg*4+w. float4 I/O.
// ---------------------------------------------------------------------------
__global__ __launch_bounds__(256) void k_conv(
    const float* __restrict__ data,
    const float* __restrict__ Kmat,
    const float* __restrict__ W_in,
    const float* __restrict__ b_in,
    const float* __restrict__ Dvec,
    float* __restrict__ ygelu)
{
    const int b    = blockIdx.x;
    const int hg   = blockIdx.y;        // 0..31
    const int tid  = threadIdx.x;
    const int wave = tid >> 6;
    const int lane = tid & 63;
    const int h    = hg*4 + wave;

    __shared__ float xrev[Ld];
    {
        const float4* d4 = (const float4*)(data + (size_t)b*Ld);
        float4* x4 = (float4*)xrev;
        for (int j = tid; j < Ld/4; j += 256) {
            float4 v = d4[j];
            x4[(Ld/4 - 1) - j] = make_float4(v.w, v.z, v.y, v.x);
        }
    }
    __syncthreads();

    const float4* K4 = (const float4*)(Kmat + (size_t)h * Ld);
    const float4* X4 = (const float4*)xrev;
    float s = 0.0f, ks = 0.0f;
    #pragma unroll 4
    for (int m = lane; m < Ld/4; m += 64) {
        float4 kv = K4[m], xv = X4[m];
        s  += kv.x*xv.x + kv.y*xv.y + kv.z*xv.z + kv.w*xv.w;
        ks += kv.x + kv.y + kv.z + kv.w;
    }
    #pragma unroll
    for (int off = 32; off >= 1; off >>= 1) {
        s  += __shfl_xor(s,  off);
        ks += __shfl_xor(ks, off);
    }
    if (lane == 0) {
        float w  = W_in[h], bi = b_in[h];
        float ulast = data[(size_t)b*Ld + (Ld - 1)] * w + bi;
        float y  = w*s + bi*ks + ulast*Dvec[h];
        // jax.nn.gelu (approximate=True, tanh form)
        float y3 = y*y*y;
        float g  = 0.5f*y*(1.0f + tanhf(0.7978845608028654f*(y + 0.044715f*y3)));
        ygelu[b*Hd + h] = g;
    }
}

// ---------------------------------------------------------------------------
// Kernel 3: per batch b: z = y @ W_glu + b_glu (128->256);
//   glu = z[:128] * sigmoid(z[128:]); out[b] = glu . W_out + b_out
// ---------------------------------------------------------------------------
__global__ __launch_bounds__(256) void k_glu_out(
    const float* __restrict__ ygelu,
    const float* __restrict__ W_glu,
    const float* __restrict__ b_glu,
    const float* __restrict__ W_out,
    const float* __restrict__ b_out,
    float* __restrict__ out)
{
    const int b = blockIdx.x;
    const int j = threadIdx.x;          // 0..255
    __shared__ float y[Hd];
    __shared__ float z[2*Hd];
    __shared__ float partial[4];

    if (j < Hd) y[j] = ygelu[b*Hd + j];
    __syncthreads();

    float zz = b_glu[j];
    #pragma unroll 8
    for (int hh = 0; hh < Hd; ++hh)
        zz += y[hh] * W_glu[hh*(2*Hd) + j];
    z[j] = zz;
    __syncthreads();

    float g = 0.0f;
    if (j < Hd) {
        float sig = 1.0f / (1.0f + expf(-z[j + Hd]));
        g = z[j] * sig * W_out[j];
    }
    #pragma unroll
    for (int off = 32; off >= 1; off >>= 1) g += __shfl_xor(g, off);
    if ((j & 63) == 0) partial[j >> 6] = g;
    __syncthreads();
    if (j == 0) out[b] = partial[0] + partial[1] + partial[2] + partial[3] + b_out[0];
}

// ---------------------------------------------------------------------------
extern "C" void kernel_launch(void* const* d_in, const int* in_sizes, int n_in,
                              void* d_out, int out_size, void* d_ws, size_t ws_size,
                              hipStream_t stream) {
    const float* data   = (const float*)d_in[0];
    const float* W_in   = (const float*)d_in[1];
    const float* b_in   = (const float*)d_in[2];
    const float* log_dt = (const float*)d_in[3];
    const float* log_A  = (const float*)d_in[4];
    const float* A_im   = (const float*)d_in[5];
    const float* C_re   = (const float*)d_in[6];
    const float* C_im   = (const float*)d_in[7];
    const float* Dvec   = (const float*)d_in[8];
    const float* W_glu  = (const float*)d_in[9];
    const float* b_glu  = (const float*)d_in[10];
    const float* W_out  = (const float*)d_in[11];
    const float* b_out  = (const float*)d_in[12];
    float* out = (float*)d_out;

    float* K     = (float*)d_ws;            // Hd*Ld floats = 2 MB
    float* ygelu = K + (size_t)Hd * Ld;     // Bd*Hd floats

    k_kernelK<<<dim3(Hd, 4), 256, 0, stream>>>(log_dt, log_A, A_im, C_re, C_im, K);
    k_conv   <<<dim3(Bd, 32), 256, 0, stream>>>(data, K, W_in, b_in, Dvec, ygelu);
    k_glu_out<<<Bd, 256, 0, stream>>>(ygelu, W_glu, b_glu, W_out, b_out, out);
}

// Round 3
// 25.832 us; speedup vs baseline: 1.4067x; 1.1941x over previous
//
#include <hip/hip_runtime.h>
#include <math.h>

constexpr int Hd = 128;   // hidden
constexpr int Nd = 64;    // state size
constexpr int Ld = 4096;  // sequence length
constexpr int Bd = 32;    // batch

// ---------------------------------------------------------------------------
// Kernel A (fused): block (h, part) computes K[h, l] for l in [part*1024,
// part*1024+1024) entirely in registers/LDS, then immediately computes the
// partial convolution against all 32 batches:
//   partS[h,part,b] = sum_{l in window} K[h,l] * data[b, L-1-l]
//   partK[h,part]   = sum_{l in window} K[h,l]
// Phase in revolutions (f64) -> HW v_sin/v_cos; magnitude via exp2f.
// ---------------------------------------------------------------------------
__global__ __launch_bounds__(256) void k_fused(
    const float* __restrict__ log_dt,
    const float* __restrict__ log_A_real,
    const float* __restrict__ A_imag,
    const float* __restrict__ C_re,
    const float* __restrict__ C_im,
    const float* __restrict__ data,
    float* __restrict__ partS,     // [H][4][B]
    float* __restrict__ partK)     // [H][4]
{
    const int h    = blockIdx.x;
    const int part = blockIdx.y;       // 0..3
    const int t    = threadIdx.x;      // 0..255
    const int base = part * 1024;

    __shared__ float  sBtr[Nd], sBti[Nd], sDreL2[Nd], sSr[Nd], sSi[Nd];
    __shared__ double sRev[Nd];        // dim / (2*pi), f64
    __shared__ float  sK[1024];
    __shared__ float  sKs[4];

    if (t < Nd) {
        const int n = t;
        float dt   = expf(log_dt[h]);
        float a_re = -expf(log_A_real[h*Nd + n]);
        float a_im = A_imag[h*Nd + n];
        float dre  = dt * a_re, dim = dt * a_im;
        float er = expf(dre);
        float sn, cs; sincosf(dim, &sn, &cs);
        float em1_re = er*cs - 1.0f;
        float em1_im = er*sn;
        // (e-1)/A = (e-1)*conj(A)/|A|^2
        float inv  = 1.0f / (a_re*a_re + a_im*a_im);
        float q_re = (em1_re*a_re + em1_im*a_im) * inv;
        float q_im = (em1_im*a_re - em1_re*a_im) * inv;
        float c_re = C_re[h*Nd + n], c_im = C_im[h*Nd + n];
        sBtr[n] = c_re*q_re - c_im*q_im;
        sBti[n] = c_re*q_im + c_im*q_re;

        float dreL2 = dre * 1.4426950408889634f;                       // dre*log2(e)
        double rev  = (double)dt * (double)a_im * 0.15915494309189535; // dim/2pi
        sDreL2[n] = dreL2;
        sRev[n]   = rev;
        // step256 = exp(dtA*256)
        float er2 = exp2f(dreL2 * 256.0f);
        double r2 = rev * 256.0;  r2 -= floor(r2);
        float fr2 = (float)r2;
        sSr[n] = er2 * __builtin_amdgcn_cosf(fr2);
        sSi[n] = er2 * __builtin_amdgcn_sinf(fr2);
    }
    __syncthreads();

    // ---- K generation: l = base + t + 256*{0,1,2,3} ----
    float acc0 = 0.f, acc1 = 0.f, acc2 = 0.f, acc3 = 0.f;
    const float  l0f = (float)(base + t);
    const double l0d = (double)(base + t);
    #pragma unroll 4
    for (int n = 0; n < Nd; ++n) {
        const float btr = sBtr[n], bti = sBti[n];
        const float sr  = sSr[n],  si  = sSi[n];
        float  er = exp2f(sDreL2[n] * l0f);
        double rv = sRev[n] * l0d;  rv -= floor(rv);
        float  fr = (float)rv;
        float  sn = __builtin_amdgcn_sinf(fr);
        float  cs = __builtin_amdgcn_cosf(fr);
        float  pr = er*cs, pi = er*sn;

        acc0 += btr*pr - bti*pi;
        float tmp = pr*sr - pi*si; pi = pr*si + pi*sr; pr = tmp;
        acc1 += btr*pr - bti*pi;
        tmp = pr*sr - pi*si; pi = pr*si + pi*sr; pr = tmp;
        acc2 += btr*pr - bti*pi;
        tmp = pr*sr - pi*si; pi = pr*si + pi*sr; pr = tmp;
        acc3 += btr*pr - bti*pi;
    }
    sK[t]       = 2.0f*acc0;
    sK[t + 256] = 2.0f*acc1;
    sK[t + 512] = 2.0f*acc2;
    sK[t + 768] = 2.0f*acc3;

    const int wave = t >> 6, lane = t & 63;
    // partial K-sum (for the b_in term)
    float ksl = 2.0f*(acc0 + acc1 + acc2 + acc3);
    #pragma unroll
    for (int off = 32; off >= 1; off >>= 1) ksl += __shfl_xor(ksl, off);
    if (lane == 0) sKs[wave] = ksl;
    __syncthreads();
    if (t == 0) partK[h*4 + part] = sKs[0] + sKs[1] + sKs[2] + sKs[3];

    // ---- partial convolution: wave w handles b = w*8 .. w*8+7 ----
    const float4* sK4 = (const float4*)sK;
    #pragma unroll
    for (int bi = 0; bi < 8; ++bi) {
        const int b = wave*8 + bi;
        const float* xb = data + (size_t)b * Ld;
        float s = 0.0f;
        #pragma unroll
        for (int j = 0; j < 4; ++j) {
            const int ll = (lane + 64*j) * 4;          // 0..1020 step 4
            float4 kv = sK4[lane + 64*j];
            // x[l] = data[b, 4095 - (base+ll+c)], c=0..3  -> reversed float4
            float4 xv = *(const float4*)(xb + (4092 - base - ll));
            s += kv.x*xv.w + kv.y*xv.z + kv.z*xv.y + kv.w*xv.x;
        }
        #pragma unroll
        for (int off = 32; off >= 1; off >>= 1) s += __shfl_xor(s, off);
        if (lane == 0) partS[(h*4 + part)*Bd + b] = s;
    }
}

// ---------------------------------------------------------------------------
// Kernel B: per batch b (32 blocks, 256 threads):
//   y[h] = W_in[h]*s + b_in[h]*ks + u_last*D[h];  gelu
//   z = y @ W_glu + b_glu; glu = z[:128]*sigmoid(z[128:]); out = glu.W_out+b_out
// ---------------------------------------------------------------------------
__global__ __launch_bounds__(256) void k_tail(
    const float* __restrict__ data,
    const float* __restrict__ partS,
    const float* __restrict__ partK,
    const float* __restrict__ W_in,
    const float* __restrict__ b_in,
    const float* __restrict__ Dvec,
    const float* __restrict__ W_glu,
    const float* __restrict__ b_glu,
    const float* __restrict__ W_out,
    const float* __restrict__ b_out,
    float* __restrict__ out)
{
    const int b = blockIdx.x;
    const int j = threadIdx.x;          // 0..255
    __shared__ float sy[Hd];
    __shared__ float z[2*Hd];
    __shared__ float partial[4];

    if (j < Hd) {
        const int h = j;
        float s  = partS[(h*4+0)*Bd + b] + partS[(h*4+1)*Bd + b]
                 + partS[(h*4+2)*Bd + b] + partS[(h*4+3)*Bd + b];
        float ks = partK[h*4+0] + partK[h*4+1] + partK[h*4+2] + partK[h*4+3];
        float w  = W_in[h], bi = b_in[h];
        float ulast = data[(size_t)b*Ld + (Ld - 1)] * w + bi;
        float y  = w*s + bi*ks + ulast*Dvec[h];
        float y3 = y*y*y;
        sy[h] = 0.5f*y*(1.0f + tanhf(0.7978845608028654f*(y + 0.044715f*y3)));
    }
    __syncthreads();

    float zz = b_glu[j];
    #pragma unroll 8
    for (int hh = 0; hh < Hd; ++hh)
        zz += sy[hh] * W_glu[hh*(2*Hd) + j];
    z[j] = zz;
    __syncthreads();

    float g = 0.0f;
    if (j < Hd) {
        float sig = 1.0f / (1.0f + expf(-z[j + Hd]));
        g = z[j] * sig * W_out[j];
    }
    #pragma unroll
    for (int off = 32; off >= 1; off >>= 1) g += __shfl_xor(g, off);
    if ((j & 63) == 0) partial[j >> 6] = g;
    __syncthreads();
    if (j == 0) out[b] = partial[0] + partial[1] + partial[2] + partial[3] + b_out[0];
}

// ---------------------------------------------------------------------------
extern "C" void kernel_launch(void* const* d_in, const int* in_sizes, int n_in,
                              void* d_out, int out_size, void* d_ws, size_t ws_size,
                              hipStream_t stream) {
    const float* data   = (const float*)d_in[0];
    const float* W_in   = (const float*)d_in[1];
    const float* b_in   = (const float*)d_in[2];
    const float* log_dt = (const float*)d_in[3];
    const float* log_A  = (const float*)d_in[4];
    const float* A_im   = (const float*)d_in[5];
    const float* C_re   = (const float*)d_in[6];
    const float* C_im   = (const float*)d_in[7];
    const float* Dvec   = (const float*)d_in[8];
    const float* W_glu  = (const float*)d_in[9];
    const float* b_glu  = (const float*)d_in[10];
    const float* W_out  = (const float*)d_in[11];
    const float* b_out  = (const float*)d_in[12];
    float* out = (float*)d_out;

    float* partS = (float*)d_ws;                 // H*4*B floats = 64 KB
    float* partK = partS + (size_t)Hd*4*Bd;      // H*4 floats

    k_fused<<<dim3(Hd, 4), 256, 0, stream>>>(log_dt, log_A, A_im, C_re, C_im,
                                             data, partS, partK);
    k_tail <<<Bd, 256, 0, stream>>>(data, partS, partK, W_in, b_in, Dvec,
                                    W_glu, b_glu, W_out, b_out, out);
}